// Round 4
// baseline (171.065 us; speedup 1.0000x reference)
//
#include <hip/hip_runtime.h>
#include <cstdint>
#include <cstddef>

// Problem constants
constexpr int N = 4096;
constexpr int B = 32;
constexpr int BN = B * N;             // 131072
constexpr size_t NN = (size_t)N * N;  // 16777216

constexpr int JCH = 8;                // j-split for fused SWT partials
constexpr int JC = N / JCH;           // 512 cols per chunk
constexpr int KCH = 8;                // k-split for SW pass partials
constexpr int KC = N / KCH;           // 512 rows per chunk

constexpr float ALPHA = 0.025f;
constexpr float BETA = 0.00025f;
constexpr float T_NOW = 10.0f;
constexpr float INV_EXP_TAU = 0.02f;          // 1/50
constexpr float INV_TAU_V = 0.98019867f;      // exp(-1/50)
constexpr float INV_TAU_I = 0.36787944f;      // exp(-1)

typedef __attribute__((ext_vector_type(8))) short short8;
typedef __attribute__((ext_vector_type(4))) float f32x4;

__device__ inline unsigned short f2bf(float f) {
  uint32_t u = __float_as_uint(f);
  u += 0x7FFFu + ((u >> 16) & 1u);   // RNE
  return (unsigned short)(u >> 16);
}

// ---------------------------------------------------------------------------
// Pass A: per-neuron spike masks + max_st + rowfac; writes S (f32) and S_bf
// (bf16 copy, the MFMA A-matrix).
// ---------------------------------------------------------------------------
__global__ __launch_bounds__(256) void pass_a(
    const float* __restrict__ mem_pot, const float* __restrict__ mem_pot_p,
    const float* __restrict__ st, float* __restrict__ S_out,
    unsigned short* __restrict__ S_bf,
    uint32_t* __restrict__ maskS, uint32_t* __restrict__ maskSP,
    float* __restrict__ max_st, float* __restrict__ rowfac) {
  int j = blockIdx.x * blockDim.x + threadIdx.x;
  if (j >= N) return;
  float stj = st[j];
  uint32_t ms = 0u, msp = 0u;
  float maxv = -3.0e38f;
  #pragma unroll
  for (int b = 0; b < B; ++b) {
    float p = mem_pot[b * N + j];
    float pp = mem_pot_p[b * N + j];
    bool s = (p - 1.0f) > 0.0f;
    bool sp = ((pp - 1.0f) - ALPHA) > 0.0f;
    S_out[b * N + j] = s ? 1.0f : 0.0f;
    S_bf[b * N + j] = s ? 0x3F80u : 0u;   // bf16 1.0 / 0.0
    ms |= (uint32_t)s << b;
    msp |= (uint32_t)sp << b;
    maxv = fmaxf(maxv, s ? T_NOW : stj);
  }
  maskS[j] = ms;
  maskSP[j] = msp;
  max_st[j] = maxv;
  rowfac[j] = msp ? ALPHA : 0.0f;
}

// ---------------------------------------------------------------------------
// Pass B (fused): compute W_new AND accumulate SWT = S @ W_new^T via MFMA,
// consuming W_new straight from registers (lane's 8 computed cols of its row
// == exactly one mfma_16x16x32 B-operand fragment, B[k=j][n=i]).
//
// Wave w handles 16 rows: i = i0 + (lane&15), i0 = blockIdx.x*64 + w*16.
// j-chunk jc = blockIdx.y covers cols [jc*JC, jc*JC+JC) in steps of 32;
// lane's cols per step: jbase + quad*8 .. +8.
// SWT partials: JCH buffers; block (rowblk, jc) writes disjoint i-range of
// buffer jc -> no atomics.
// ---------------------------------------------------------------------------
__global__ __launch_bounds__(256) void pass_b(
    const float* __restrict__ W, const unsigned short* __restrict__ S_bf,
    const float* __restrict__ max_st, const float* __restrict__ rowfac,
    float* __restrict__ Wout, float* __restrict__ partSWT) {
  int wv = threadIdx.x >> 6;
  int lane = threadIdx.x & 63;
  int nl = lane & 15;
  int quad = lane >> 4;
  int i = blockIdx.x * 64 + wv * 16 + nl;   // this lane's row
  int jc = blockIdx.y;

  float mst_i = max_st[i];
  float fac_i = rowfac[i];
  const float* __restrict__ Wrow = W + (size_t)i * N;
  float* __restrict__ WoRow = Wout + (size_t)i * N;
  const unsigned short* __restrict__ A0p = S_bf + (size_t)nl * N;
  const unsigned short* __restrict__ A1p = S_bf + (size_t)(nl + 16) * N;

  f32x4 acc0 = {0.f, 0.f, 0.f, 0.f};
  f32x4 acc1 = {0.f, 0.f, 0.f, 0.f};

  auto upd = [&](float ww, float mstj) -> float {
    float d = fabsf(mst_i - mstj);
    float ex = __expf(d * INV_EXP_TAU);
    float u = ww + BETA - fac_i * ex;
    u = fminf(fmaxf(u, 0.0f), 1.0f);
    return (ww > 0.0f) ? u : ww;
  };

  #pragma unroll 2
  for (int it = 0; it < JC / 32; ++it) {
    int j = jc * JC + it * 32 + quad * 8;   // this lane's 8 cols
    float4 w0 = *(const float4*)(Wrow + j);
    float4 w1 = *(const float4*)(Wrow + j + 4);
    float4 m0 = *(const float4*)(max_st + j);
    float4 m1 = *(const float4*)(max_st + j + 4);
    short8 a0 = *(const short8*)(A0p + j);
    short8 a1 = *(const short8*)(A1p + j);

    float4 o0, o1;
    o0.x = upd(w0.x, m0.x); o0.y = upd(w0.y, m0.y);
    o0.z = upd(w0.z, m0.z); o0.w = upd(w0.w, m0.w);
    o1.x = upd(w1.x, m1.x); o1.y = upd(w1.y, m1.y);
    o1.z = upd(w1.z, m1.z); o1.w = upd(w1.w, m1.w);
    *(float4*)(WoRow + j) = o0;
    *(float4*)(WoRow + j + 4) = o1;

    short8 bf;
    bf[0] = (short)f2bf(o0.x); bf[1] = (short)f2bf(o0.y);
    bf[2] = (short)f2bf(o0.z); bf[3] = (short)f2bf(o0.w);
    bf[4] = (short)f2bf(o1.x); bf[5] = (short)f2bf(o1.y);
    bf[6] = (short)f2bf(o1.z); bf[7] = (short)f2bf(o1.w);

    acc0 = __builtin_amdgcn_mfma_f32_16x16x32_bf16(a0, bf, acc0, 0, 0, 0);
    acc1 = __builtin_amdgcn_mfma_f32_16x16x32_bf16(a1, bf, acc1, 0, 0, 0);
  }

  // C/D layout: lane(nl,quad) reg r -> D[m=quad*4+r][n=nl];
  // m = batch, n = local row index -> global row i.
  size_t base = (size_t)jc * BN + (size_t)(blockIdx.x * 64 + wv * 16 + nl);
  #pragma unroll
  for (int r = 0; r < 4; ++r) {
    partSWT[base + (size_t)(quad * 4 + r) * N] = acc0[r];
    partSWT[base + (size_t)(16 + quad * 4 + r) * N] = acc1[r];
  }
}

// ---------------------------------------------------------------------------
// Pass SW: SW[b,j] = sum_k S[b,k] * W_new[k,j] via MFMA; W_new read back
// (L2/L3-warm). K split into KCH non-atomic partial buffers.
// ---------------------------------------------------------------------------
__global__ __launch_bounds__(256) void pass_sw(
    const float* __restrict__ Wn, const unsigned short* __restrict__ S_bf,
    float* __restrict__ partSW) {
  int wv = threadIdx.x >> 6;
  int lane = threadIdx.x & 63;
  int ntile = blockIdx.x * 4 + wv;     // 0..255
  int j0 = ntile * 16;
  int kchunk = blockIdx.y;
  int kbase = kchunk * KC;
  int quad = lane >> 4;
  int nl = lane & 15;

  f32x4 acc0 = {0.f, 0.f, 0.f, 0.f};
  f32x4 acc1 = {0.f, 0.f, 0.f, 0.f};
  const unsigned short* __restrict__ A0p = S_bf + (size_t)nl * N;
  const unsigned short* __restrict__ A1p = S_bf + (size_t)(nl + 16) * N;

  #pragma unroll 4
  for (int it = 0; it < KC / 32; ++it) {
    int k0 = kbase + it * 32;
    short8 a0 = *(const short8*)(A0p + k0 + quad * 8);
    short8 a1 = *(const short8*)(A1p + k0 + quad * 8);
    short8 bf;
    #pragma unroll
    for (int i = 0; i < 8; ++i) {
      float f = Wn[(size_t)(k0 + quad * 8 + i) * N + j0 + nl];
      bf[i] = (short)f2bf(f);
    }
    acc0 = __builtin_amdgcn_mfma_f32_16x16x32_bf16(a0, bf, acc0, 0, 0, 0);
    acc1 = __builtin_amdgcn_mfma_f32_16x16x32_bf16(a1, bf, acc1, 0, 0, 0);
  }

  size_t base = (size_t)kchunk * BN + j0 + nl;
  #pragma unroll
  for (int r = 0; r < 4; ++r) {
    partSW[base + (size_t)(quad * 4 + r) * N] = acc0[r];
    partSW[base + (size_t)(16 + quad * 4 + r) * N] = acc1[r];
  }
}

// ---------------------------------------------------------------------------
// Pass D: reduce partials, integrate + leak + reset + refractory.
// ---------------------------------------------------------------------------
__global__ __launch_bounds__(256) void pass_d(
    const float* __restrict__ inp, const float* __restrict__ mem_pot,
    const float* __restrict__ mem_cur, const float* __restrict__ mem_pot_p,
    const float* __restrict__ mem_cur_p, const int* __restrict__ refrac_in,
    const uint32_t* __restrict__ maskS, const uint32_t* __restrict__ maskSP,
    const float* __restrict__ partSW, const float* __restrict__ partSWT,
    float* __restrict__ pot_out, float* __restrict__ cur_out,
    float* __restrict__ potp_out, float* __restrict__ curp_out,
    float* __restrict__ refrac_out) {
  int e = blockIdx.x * 256 + threadIdx.x;
  int b = e >> 12;
  int j = e & (N - 1);

  float SW = 0.0f, SWT = 0.0f;
  #pragma unroll
  for (int c = 0; c < KCH; ++c) SW += partSW[(size_t)c * BN + e];
  #pragma unroll
  for (int c = 0; c < JCH; ++c) SWT += partSWT[(size_t)c * BN + e];

  int r = refrac_in[e];
  int rd = (r > 0) ? (r - 1) : r;
  bool active = (rd == 0);
  bool s = (maskS[j] >> b) & 1u;
  bool sp = (maskSP[j] >> b) & 1u;
  float cur = mem_cur[e], pot = mem_pot[e];
  float curp = mem_cur_p[e], potp = mem_pot_p[e];

  float cur_n = active ? (inp[e] + SW + cur) : cur;
  float curp_n = active ? (SWT + curp) : curp;
  float pot_n = active ? (cur_n + pot) : pot;
  float potp_n = active ? (curp_n + potp) : potp;

  pot_n *= INV_TAU_V;
  cur_n *= INV_TAU_I;
  potp_n *= INV_TAU_V;
  curp_n *= INV_TAU_I;

  if (s) pot_n = 0.0f;
  if (sp) potp_n = 0.0f;
  int rn = s ? 2 : rd;

  pot_out[e] = pot_n;
  cur_out[e] = cur_n;
  potp_out[e] = potp_n;
  curp_out[e] = curp_n;
  refrac_out[e] = (float)rn;
}

// ---------------------------------------------------------------------------
extern "C" void kernel_launch(void* const* d_in, const int* in_sizes, int n_in,
                              void* d_out, int out_size, void* d_ws, size_t ws_size,
                              hipStream_t stream) {
  const float* inp = (const float*)d_in[0];
  const float* W = (const float*)d_in[1];
  const float* mem_pot = (const float*)d_in[2];
  const float* mem_cur = (const float*)d_in[3];
  const float* mem_pot_p = (const float*)d_in[4];
  const float* mem_cur_p = (const float*)d_in[5];
  const float* st = (const float*)d_in[6];
  const int* refrac = (const int*)d_in[7];

  float* out = (float*)d_out;
  float* S_out = out;
  float* pot_out = out + BN;
  float* W_out = out + 2 * (size_t)BN;
  float* cur_out = W_out + NN;
  float* potp_out = cur_out + BN;
  float* curp_out = potp_out + BN;
  float* refrac_out = curp_out + BN;

  // Workspace layout (16B-aligned), ~8.6 MB total
  uint32_t* maskS = (uint32_t*)d_ws;                      // 16 KB
  uint32_t* maskSP = maskS + N;                           // 16 KB
  float* max_st = (float*)(maskSP + N);                   // 16 KB
  float* rowfac = max_st + N;                             // 16 KB
  unsigned short* S_bf = (unsigned short*)(rowfac + N);   // 256 KB
  float* partSW = (float*)(S_bf + BN);                    // KCH*BN*4 = 4 MB
  float* partSWT = partSW + (size_t)KCH * BN;             // JCH*BN*4 = 4 MB

  pass_a<<<N / 256, 256, 0, stream>>>(mem_pot, mem_pot_p, st, S_out, S_bf,
                                      maskS, maskSP, max_st, rowfac);
  pass_b<<<dim3(N / 64, JCH), 256, 0, stream>>>(W, S_bf, max_st, rowfac,
                                                W_out, partSWT);
  pass_sw<<<dim3(64, KCH), 256, 0, stream>>>(W_out, S_bf, partSW);
  pass_d<<<BN / 256, 256, 0, stream>>>(inp, mem_pot, mem_cur, mem_pot_p,
                                       mem_cur_p, refrac, maskS, maskSP,
                                       partSW, partSWT, pot_out, cur_out,
                                       potp_out, curp_out, refrac_out);
}